// Round 1
// baseline (460.376 us; speedup 1.0000x reference)
//
#include <hip/hip_runtime.h>
#include <hip/hip_bf16.h>
#include <cstdint>
#include <cstddef>

typedef __bf16 bf16x8 __attribute__((ext_vector_type(8)));
typedef float f32x4 __attribute__((ext_vector_type(4)));

#define AS1(p) ((const __attribute__((address_space(1))) void*)(p))
#define AS3(p) ((__attribute__((address_space(3))) void*)(p))

__device__ __forceinline__ unsigned short f2bf_rne(float f) {
    union { float f; unsigned u; } c; c.f = f;
    unsigned u = c.u;
    unsigned r = (u + 0x7FFFu + ((u >> 16) & 1u)) >> 16;
    return (unsigned short)r;
}

// -------- binarize: one block per output row; sign -> bf16 bits, alpha = mean|w| --------
__global__ __launch_bounds__(256)
void binarize_k(const float* __restrict__ W, unsigned short* __restrict__ Sg,
                float* __restrict__ Alpha, int C) {
    const int r = blockIdx.x;
    const float4* w = (const float4*)(W + (size_t)r * C);
    ushort4* s = (ushort4*)(Sg + (size_t)r * C);
    const int n4 = C >> 2;
    float lsum = 0.f;
    for (int i = threadIdx.x; i < n4; i += 256) {
        float4 v = w[i];
        lsum += fabsf(v.x) + fabsf(v.y) + fabsf(v.z) + fabsf(v.w);
        ushort4 o;
        o.x = (v.x == 0.f) ? 0 : ((v.x < 0.f) ? 0xBF80 : 0x3F80);
        o.y = (v.y == 0.f) ? 0 : ((v.y < 0.f) ? 0xBF80 : 0x3F80);
        o.z = (v.z == 0.f) ? 0 : ((v.z < 0.f) ? 0xBF80 : 0x3F80);
        o.w = (v.w == 0.f) ? 0 : ((v.w < 0.f) ? 0xBF80 : 0x3F80);
        s[i] = o;
    }
    for (int o = 32; o > 0; o >>= 1) lsum += __shfl_down(lsum, o, 64);
    __shared__ float red[4];
    const int lane = threadIdx.x & 63, wid = threadIdx.x >> 6;
    if (lane == 0) red[wid] = lsum;
    __syncthreads();
    if (threadIdx.x == 0) Alpha[r] = (red[0] + red[1] + red[2] + red[3]) / (float)C;
}

// -------- fp32 -> bf16 convert (vectorized) --------
__global__ __launch_bounds__(256)
void f32_to_bf16_k(const float* __restrict__ X, unsigned short* __restrict__ Y, int n4) {
    const int stride = gridDim.x * 256;
    for (int i = blockIdx.x * 256 + threadIdx.x; i < n4; i += stride) {
        float4 v = ((const float4*)X)[i];
        ushort4 o;
        o.x = f2bf_rne(v.x); o.y = f2bf_rne(v.y);
        o.z = f2bf_rne(v.z); o.w = f2bf_rne(v.w);
        ((ushort4*)Y)[i] = o;
    }
}

// -------- binary-weight GEMM: C[m,n] = act(alpha[n] * sum_k A[m,k]*S[n,k] + bias[n]) --------
// A: bf16 [M,K] row-major; S: bf16 sign [N,K] row-major (B^T layout).
// 128x128 tile, BK=64, 4 waves (2x2), each wave 64x64 via 4x4 frags of 16x16x32 MFMA.
// GELU=1: exact-erf GELU, bf16 out. GELU=0: fp32 out, no activation.
template<int GELU>
__global__ __launch_bounds__(256, 2)
void gemm_bin(const unsigned short* __restrict__ A,
              const unsigned short* __restrict__ S,
              const float* __restrict__ alpha,
              const float* __restrict__ bias,
              unsigned short* __restrict__ Obf,
              float* __restrict__ Of32,
              int M, int N, int K)
{
    __shared__ unsigned short As[128][64];
    __shared__ unsigned short Ss[128][64];

    const int tid  = threadIdx.x;
    const int lane = tid & 63;
    const int wid  = tid >> 6;
    const int wr   = wid >> 1, wc = wid & 1;

    const int nbn = N >> 7;
    const int nbm = M >> 7;
    const int nwg = nbm * nbn;          // divisible by 8 for our shapes
    const int cpx = nwg >> 3;
    const int bid = blockIdx.x;
    const int swz = (bid & 7) * cpx + (bid >> 3);   // XCD-bijective swizzle
    const int bm = swz / nbn;
    const int bn = swz % nbn;

    const unsigned short* gA = A + (size_t)bm * 128 * K;
    const unsigned short* gS = S + (size_t)bn * 128 * K;

    f32x4 acc[4][4] = {};
    const int lr = lane & 15;           // frag row (A) / col (B)
    const int lk = (lane >> 4) * 8;     // frag k offset

    const int nkt = K >> 6;
    for (int kt = 0; kt < nkt; ++kt) {
        const int k0 = kt << 6;
        // stage 16KB A-tile + 16KB S-tile: 4 rounds x 256 lanes x 16B
#pragma unroll
        for (int j = 0; j < 4; ++j) {
            const int idx = j * 256 + tid;        // 16B unit within tile
            const int r = idx >> 3;
            const int c = (idx & 7) * 8;          // element column
            __builtin_amdgcn_global_load_lds(AS1(gA + (size_t)r * K + k0 + c),
                                             AS3(&As[0][0] + idx * 8), 16, 0, 0);
            __builtin_amdgcn_global_load_lds(AS1(gS + (size_t)r * K + k0 + c),
                                             AS3(&Ss[0][0] + idx * 8), 16, 0, 0);
        }
        __syncthreads();   // compiler drains vmcnt(0) before s_barrier

        bf16x8 af[2][4], bf[2][4];
#pragma unroll
        for (int ks = 0; ks < 2; ++ks) {
#pragma unroll
            for (int mf = 0; mf < 4; ++mf)
                af[ks][mf] = *(const bf16x8*)&As[wr * 64 + mf * 16 + lr][ks * 32 + lk];
#pragma unroll
            for (int nf = 0; nf < 4; ++nf)
                bf[ks][nf] = *(const bf16x8*)&Ss[wc * 64 + nf * 16 + lr][ks * 32 + lk];
        }
#pragma unroll
        for (int ks = 0; ks < 2; ++ks)
#pragma unroll
            for (int mf = 0; mf < 4; ++mf)
#pragma unroll
                for (int nf = 0; nf < 4; ++nf)
                    acc[mf][nf] = __builtin_amdgcn_mfma_f32_16x16x32_bf16(
                        af[ks][mf], bf[ks][nf], acc[mf][nf], 0, 0, 0);
        __syncthreads();
    }

    // epilogue: alpha*acc + bias, optional GELU, store
    const int col0 = bn * 128 + wc * 64;
    const int row0 = bm * 128 + wr * 64;
    float al[4], bi[4];
#pragma unroll
    for (int nf = 0; nf < 4; ++nf) {
        const int n = col0 + nf * 16 + lr;
        al[nf] = alpha[n];
        bi[nf] = bias[n];
    }
#pragma unroll
    for (int mf = 0; mf < 4; ++mf) {
#pragma unroll
        for (int j = 0; j < 4; ++j) {
            const int m = row0 + mf * 16 + (lane >> 4) * 4 + j;
#pragma unroll
            for (int nf = 0; nf < 4; ++nf) {
                const int n = col0 + nf * 16 + lr;
                float v = acc[mf][nf][j] * al[nf] + bi[nf];
                if (GELU) {
                    v = 0.5f * v * (1.0f + erff(v * 0.70710678118654752f));
                    Obf[(size_t)m * N + n] = f2bf_rne(v);
                } else {
                    Of32[(size_t)m * N + n] = v;
                }
            }
        }
    }
}

extern "C" void kernel_launch(void* const* d_in, const int* in_sizes, int n_in,
                              void* d_out, int out_size, void* d_ws, size_t ws_size,
                              hipStream_t stream) {
    const float* x  = (const float*)d_in[0];
    const float* w1 = (const float*)d_in[1];
    const float* b1 = (const float*)d_in[2];
    const float* w2 = (const float*)d_in[3];
    const float* b2 = (const float*)d_in[4];
    float* out = (float*)d_out;

    const int D = 1024, H = 4096;
    const int M = in_sizes[0] / D;   // 12544 = 98*128

    char* ws = (char*)d_ws;
    size_t off = 0;
    auto alloc = [&](size_t bytes) -> void* {
        void* p = ws + off;
        off = (off + bytes + 255) & ~(size_t)255;
        return p;
    };
    unsigned short* xb = (unsigned short*)alloc((size_t)M * D * 2);   // x in bf16
    unsigned short* s1 = (unsigned short*)alloc((size_t)H * D * 2);   // sign(w1) bf16
    float*          a1 = (float*)alloc((size_t)H * 4);                // alpha1
    unsigned short* s2 = (unsigned short*)alloc((size_t)D * H * 2);   // sign(w2) bf16
    float*          a2 = (float*)alloc((size_t)D * 4);                // alpha2
    unsigned short* hb = (unsigned short*)alloc((size_t)M * H * 2);   // gelu(h) bf16

    binarize_k<<<H, 256, 0, stream>>>(w1, s1, a1, D);
    binarize_k<<<D, 256, 0, stream>>>(w2, s2, a2, H);
    f32_to_bf16_k<<<2048, 256, 0, stream>>>(x, xb, (M * D) / 4);

    gemm_bin<1><<<(M / 128) * (H / 128), 256, 0, stream>>>(xb, s1, a1, b1, hb, nullptr, M, H, D);
    gemm_bin<0><<<(M / 128) * (D / 128), 256, 0, stream>>>(hb, s2, a2, b2, nullptr, out, M, D, H);
}

// Round 2
// 393.927 us; speedup vs baseline: 1.1687x; 1.1687x over previous
//
#include <hip/hip_runtime.h>
#include <hip/hip_bf16.h>
#include <cstdint>
#include <cstddef>

typedef __bf16 bf16x8 __attribute__((ext_vector_type(8)));
typedef float f32x4 __attribute__((ext_vector_type(4)));

#define AS1(p) ((const __attribute__((address_space(1))) void*)(p))
#define AS3(p) ((__attribute__((address_space(3))) void*)(p))

__device__ __forceinline__ unsigned short f2bf_rne(float f) {
    union { float f; unsigned u; } c; c.f = f;
    unsigned u = c.u;
    unsigned r = (u + 0x7FFFu + ((u >> 16) & 1u)) >> 16;
    return (unsigned short)r;
}

// -------- binarize: one block per output row; sign -> bf16 bits, alpha = mean|w| --------
__global__ __launch_bounds__(256)
void binarize_k(const float* __restrict__ W, unsigned short* __restrict__ Sg,
                float* __restrict__ Alpha, int C) {
    const int r = blockIdx.x;
    const float4* w = (const float4*)(W + (size_t)r * C);
    ushort4* s = (ushort4*)(Sg + (size_t)r * C);
    const int n4 = C >> 2;
    float lsum = 0.f;
    for (int i = threadIdx.x; i < n4; i += 256) {
        float4 v = w[i];
        lsum += fabsf(v.x) + fabsf(v.y) + fabsf(v.z) + fabsf(v.w);
        ushort4 o;
        o.x = (v.x == 0.f) ? 0 : ((v.x < 0.f) ? 0xBF80 : 0x3F80);
        o.y = (v.y == 0.f) ? 0 : ((v.y < 0.f) ? 0xBF80 : 0x3F80);
        o.z = (v.z == 0.f) ? 0 : ((v.z < 0.f) ? 0xBF80 : 0x3F80);
        o.w = (v.w == 0.f) ? 0 : ((v.w < 0.f) ? 0xBF80 : 0x3F80);
        s[i] = o;
    }
    for (int o = 32; o > 0; o >>= 1) lsum += __shfl_down(lsum, o, 64);
    __shared__ float red[4];
    const int lane = threadIdx.x & 63, wid = threadIdx.x >> 6;
    if (lane == 0) red[wid] = lsum;
    __syncthreads();
    if (threadIdx.x == 0) Alpha[r] = (red[0] + red[1] + red[2] + red[3]) / (float)C;
}

// -------- fp32 -> bf16 convert (vectorized) --------
__global__ __launch_bounds__(256)
void f32_to_bf16_k(const float* __restrict__ X, unsigned short* __restrict__ Y, int n4) {
    const int stride = gridDim.x * 256;
    for (int i = blockIdx.x * 256 + threadIdx.x; i < n4; i += stride) {
        float4 v = ((const float4*)X)[i];
        ushort4 o;
        o.x = f2bf_rne(v.x); o.y = f2bf_rne(v.y);
        o.z = f2bf_rne(v.z); o.w = f2bf_rne(v.w);
        ((ushort4*)Y)[i] = o;
    }
}

// -------- 256x256 8-phase binary-weight GEMM --------
// C[m,n] = act(alpha[n] * sum_k A[m,k]*S[n,k] + bias[n])
// A bf16 [M,K] row-major, S bf16 sign [N,K] row-major.
// 512 thr = 8 waves (2M x 4N); per-wave 128x64 out = acc[8][4] of 16x16 frags.
// LDS 128KB: [buf2][A/B][half2][128*64] bf16; XOR slot-swizzle (slot ^= row&7),
// applied on stage (pre-swizzled global src, linear LDS dest) and on ds_read.
// 8 phases / 2 K-tiles; counted vmcnt(4) at phases 3 and 7 only (never 0).
template<int GELU>
__global__ __launch_bounds__(512, 2)
void gemm_bin8(const unsigned short* __restrict__ A,
               const unsigned short* __restrict__ S,
               const float* __restrict__ alpha,
               const float* __restrict__ bias,
               unsigned short* __restrict__ Obf,
               float* __restrict__ Of32,
               int M, int N, int K)
{
    __shared__ __align__(16) unsigned short lds[2][2][2][128 * 64];

    const int tid  = threadIdx.x;
    const int lane = tid & 63;
    const int wid  = tid >> 6;
    const int wr   = wid >> 2;        // 0..1  -> A half / output row block
    const int wc   = wid & 3;         // 0..3  -> output col block
    const int lr   = lane & 15;
    const int hi   = lane >> 4;       // 0..3
    const int xorv = lr & 7;          // read-side swizzle xor

    // bijective XCD-aware block swizzle (m204 form; works for nwg%8 != 0)
    const int nbn = N >> 8, nbm = M >> 8;
    const int nwg = nbm * nbn;
    const int q = nwg >> 3, r = nwg & 7;
    const int xcd = blockIdx.x & 7, loc = blockIdx.x >> 3;
    const int swz = (xcd < r ? xcd * (q + 1) : r * (q + 1) + (xcd - r) * q) + loc;
    const int bm = swz / nbn, bn = swz % nbn;

    const unsigned short* gA = A + (size_t)bm * 256 * K;
    const unsigned short* gB = S + (size_t)bn * 256 * K;

    const unsigned short* Ab[2] = { &lds[0][0][wr][0], &lds[1][0][wr][0] };
    const unsigned short* Bb[2] = { &lds[0][1][wc >> 1][0], &lds[1][1][wc >> 1][0] };
    const int brow = (wc & 1) * 64;

    f32x4 acc[8][4] = {};
    bf16x8 af[2][4], bq0[2][2], bq1[2][2];

    const int T = K >> 6;
    const int niter = T >> 1;

// stage one half-tile (128 rows x 64 cols): linear LDS dest, inverse-swizzled global src
#define STAGE(BUF_, MAT_, HALF_, TILE_, GSRC_) do {                                   \
    const unsigned short* _g = (GSRC_) + (size_t)(HALF_) * 128 * K + ((TILE_) << 6);  \
    unsigned short* _l = &lds[BUF_][MAT_][HALF_][0];                                  \
    _Pragma("unroll")                                                                 \
    for (int _rd = 0; _rd < 2; ++_rd) {                                               \
        const int _u = _rd * 512 + tid;                                               \
        const int _row = _u >> 3;                                                     \
        const int _sc = ((_u & 7) ^ (_row & 7)) << 3;                                 \
        __builtin_amdgcn_global_load_lds(AS1(_g + (size_t)_row * K + _sc),            \
                                         AS3(_l + _u * 8), 16, 0, 0);                 \
    }                                                                                 \
} while (0)

#define LOAD_AF(BUF_, MB_) do {                                                       \
    _Pragma("unroll")                                                                 \
    for (int _ks = 0; _ks < 2; ++_ks)                                                 \
    _Pragma("unroll")                                                                 \
    for (int _mf = 0; _mf < 4; ++_mf)                                                 \
        af[_ks][_mf] = *(const bf16x8*)(Ab[BUF_] + (((MB_)*4 + _mf) * 16 + lr) * 64   \
                                        + (((_ks << 2) + hi) ^ xorv) * 8);            \
} while (0)

#define LOAD_BF(ARR_, BUF_, NB_) do {                                                 \
    _Pragma("unroll")                                                                 \
    for (int _ks = 0; _ks < 2; ++_ks)                                                 \
    _Pragma("unroll")                                                                 \
    for (int _nf = 0; _nf < 2; ++_nf)                                                 \
        ARR_[_ks][_nf] = *(const bf16x8*)(Bb[BUF_] + (brow + ((NB_)*2 + _nf) * 16 + lr) * 64 \
                                          + (((_ks << 2) + hi) ^ xorv) * 8);          \
} while (0)

#define MFMA_Q(MB_, ARR_, NB_) do {                                                   \
    _Pragma("unroll")                                                                 \
    for (int _ks = 0; _ks < 2; ++_ks)                                                 \
    _Pragma("unroll")                                                                 \
    for (int _mf = 0; _mf < 4; ++_mf)                                                 \
    _Pragma("unroll")                                                                 \
    for (int _nf = 0; _nf < 2; ++_nf)                                                 \
        acc[(MB_)*4 + _mf][(NB_)*2 + _nf] = __builtin_amdgcn_mfma_f32_16x16x32_bf16(  \
            af[_ks][_mf], ARR_[_ks][_nf], acc[(MB_)*4 + _mf][(NB_)*2 + _nf], 0, 0, 0);\
} while (0)

#define BAR() __builtin_amdgcn_s_barrier()
#define VMW4() asm volatile("s_waitcnt vmcnt(4)" ::: "memory")

    // prologue: tile0 full -> buf0; tile1 B-halves -> buf1; A(t1) staged in-loop P0/P1
    STAGE(0, 1, 0, 0, gB); STAGE(0, 1, 1, 0, gB);
    STAGE(0, 0, 0, 0, gA); STAGE(0, 0, 1, 0, gA);
    STAGE(1, 1, 0, 1, gB); STAGE(1, 1, 1, 1, gB);
    VMW4();
    BAR();

    for (int i = 0; i < niter; ++i) {
        const int t  = 2 * i;
        const int t1 = t + 1;
        const int t2 = (t + 2 < T) ? t + 2 : 0;   // wrap on last iter: staged but never read
        const int t3 = (t + 3 < T) ? t + 3 : 1;

        // P0: reads buf0(tile t) af0-3 + b(nf0-1); stage buf1.Ah0 <- t1
        LOAD_AF(0, 0); LOAD_BF(bq0, 0, 0);
        STAGE(1, 0, 0, t1, gA);
        BAR(); __builtin_amdgcn_s_setprio(1); MFMA_Q(0, bq0, 0); __builtin_amdgcn_s_setprio(0); BAR();
        // P1: reads b(nf2-3); stage buf1.Ah1 <- t1
        LOAD_BF(bq1, 0, 1);
        STAGE(1, 0, 1, t1, gA);
        BAR(); __builtin_amdgcn_s_setprio(1); MFMA_Q(0, bq1, 1); __builtin_amdgcn_s_setprio(0); BAR();
        // P2: reads af4-7; stage buf0.Bh0 <- t2 (buf0.B free after P1)
        LOAD_AF(0, 1);
        STAGE(0, 1, 0, t2, gB);
        BAR(); __builtin_amdgcn_s_setprio(1); MFMA_Q(1, bq0, 0); __builtin_amdgcn_s_setprio(0); BAR();
        // P3: stage buf0.Bh1 <- t2; counted wait covers A(t1) for P4
        STAGE(0, 1, 1, t2, gB);
        BAR(); __builtin_amdgcn_s_setprio(1); MFMA_Q(1, bq1, 1); __builtin_amdgcn_s_setprio(0);
        VMW4(); BAR();
        // P4: reads buf1(tile t1); stage buf0.Ah0 <- t2 (buf0.A free after P2)
        LOAD_AF(1, 0); LOAD_BF(bq0, 1, 0);
        STAGE(0, 0, 0, t2, gA);
        BAR(); __builtin_amdgcn_s_setprio(1); MFMA_Q(0, bq0, 0); __builtin_amdgcn_s_setprio(0); BAR();
        // P5: stage buf0.Ah1 <- t2
        LOAD_BF(bq1, 1, 1);
        STAGE(0, 0, 1, t2, gA);
        BAR(); __builtin_amdgcn_s_setprio(1); MFMA_Q(0, bq1, 1); __builtin_amdgcn_s_setprio(0); BAR();
        // P6: stage buf1.Bh0 <- t3 (buf1.B free after P5)
        LOAD_AF(1, 1);
        STAGE(1, 1, 0, t3, gB);
        BAR(); __builtin_amdgcn_s_setprio(1); MFMA_Q(1, bq0, 0); __builtin_amdgcn_s_setprio(0); BAR();
        // P7: stage buf1.Bh1 <- t3; counted wait covers buf0(t2) for next P0
        STAGE(1, 1, 1, t3, gB);
        BAR(); __builtin_amdgcn_s_setprio(1); MFMA_Q(1, bq1, 1); __builtin_amdgcn_s_setprio(0);
        VMW4(); BAR();
    }

    // epilogue: alpha*acc + bias, optional GELU, store
    const int col0 = bn * 256 + wc * 64;
    const int row0 = bm * 256 + wr * 128;
    float al[4], bi[4];
#pragma unroll
    for (int nf = 0; nf < 4; ++nf) {
        const int n = col0 + nf * 16 + lr;
        al[nf] = alpha[n];
        bi[nf] = bias[n];
    }
#pragma unroll
    for (int mf = 0; mf < 8; ++mf) {
#pragma unroll
        for (int j = 0; j < 4; ++j) {
            const int m = row0 + mf * 16 + hi * 4 + j;
#pragma unroll
            for (int nf = 0; nf < 4; ++nf) {
                const int n = col0 + nf * 16 + lr;
                float v = acc[mf][nf][j] * al[nf] + bi[nf];
                if (GELU) {
                    v = 0.5f * v * (1.0f + erff(v * 0.70710678118654752f));
                    Obf[(size_t)m * N + n] = f2bf_rne(v);
                } else {
                    Of32[(size_t)m * N + n] = v;
                }
            }
        }
    }
#undef STAGE
#undef LOAD_AF
#undef LOAD_BF
#undef MFMA_Q
#undef BAR
#undef VMW4
}

extern "C" void kernel_launch(void* const* d_in, const int* in_sizes, int n_in,
                              void* d_out, int out_size, void* d_ws, size_t ws_size,
                              hipStream_t stream) {
    const float* x  = (const float*)d_in[0];
    const float* w1 = (const float*)d_in[1];
    const float* b1 = (const float*)d_in[2];
    const float* w2 = (const float*)d_in[3];
    const float* b2 = (const float*)d_in[4];
    float* out = (float*)d_out;

    const int D = 1024, H = 4096;
    const int M = in_sizes[0] / D;   // 12544 = 49*256

    char* ws = (char*)d_ws;
    size_t off = 0;
    auto alloc = [&](size_t bytes) -> void* {
        void* p = ws + off;
        off = (off + bytes + 255) & ~(size_t)255;
        return p;
    };
    unsigned short* xb = (unsigned short*)alloc((size_t)M * D * 2);   // x in bf16
    unsigned short* s1 = (unsigned short*)alloc((size_t)H * D * 2);   // sign(w1) bf16
    float*          a1 = (float*)alloc((size_t)H * 4);                // alpha1
    unsigned short* s2 = (unsigned short*)alloc((size_t)D * H * 2);   // sign(w2) bf16
    float*          a2 = (float*)alloc((size_t)D * 4);                // alpha2
    unsigned short* hb = (unsigned short*)alloc((size_t)M * H * 2);   // gelu(h) bf16

    binarize_k<<<H, 256, 0, stream>>>(w1, s1, a1, D);
    binarize_k<<<D, 256, 0, stream>>>(w2, s2, a2, H);
    f32_to_bf16_k<<<2048, 256, 0, stream>>>(x, xb, (M * D) / 4);

    gemm_bin8<1><<<(M / 256) * (H / 256), 512, 0, stream>>>(xb, s1, a1, b1, hb, nullptr, M, H, D);
    gemm_bin8<0><<<(M / 256) * (D / 256), 512, 0, stream>>>(hb, s2, a2, b2, nullptr, out, M, D, H);
}